// Round 8
// baseline (62.395 us; speedup 1.0000x reference)
//
#include <hip/hip_runtime.h>

#define NB 8
#define NA 32768
#define NC 80
#define NM 32
#define NK 50
#define CAP 4096
#define TB 32                 // t2 chunks per image (1024 anchors each)
#define POS_BLOCKS (NB * NM)  // 256, bx [0,256)
#define T2_BLOCKS (TB * NB)   // 256, bx [256,512)
#define F0BLKS 512            // bx [512,1024)
#define CORRB (NA / 256)      // 128 corr blocks per image
constexpr float VAR0 = 0.1f, VAR1 = 0.2f;
constexpr float T1f  = 0.5f;
constexpr float SL1B = 0.11f;
constexpr float SL1W = 0.75f;
constexpr float FEPS = 1e-12f;

__device__ __forceinline__ float iou_corner(float tx0, float ty0, float tx1, float ty1, float ta,
                                            float bx0, float by0, float bx1, float by1, float ba) {
  float lx = fmaxf(tx0, bx0), ly = fmaxf(ty0, by0);
  float rx = fminf(tx1, bx1), ry = fminf(ty1, by1);
  float wx = fmaxf(rx - lx, 0.f), wy = fmaxf(ry - ly, 0.f);
  float inter = wx * wy;
  return inter / (ta + ba - inter);
}

__device__ __forceinline__ float focal_term(float s, float bp) {
  float pr = s * (1.f - bp);
  float om = fmaxf(1.f - pr, 1e-38f);
  return pr * pr * fminf(-__logf(om), 100.f);
}

// ---- K1: fused pos | t2 | f0 (independent roles, one dispatch, atomic-free outputs) ----
__global__ void __launch_bounds__(1024, 8) mega_kernel(const float4* __restrict__ br,
                                                       const float* __restrict__ cls,
                                                       const float4* __restrict__ anc,
                                                       const float4* __restrict__ tgt,
                                                       const int* __restrict__ labels,
                                                       unsigned* __restrict__ partmax,
                                                       unsigned* __restrict__ pairmask,
                                                       float* __restrict__ posp,
                                                       float* __restrict__ f0part) {
  // pos-role LDS (largest role dominates; ~37 KB total)
  __shared__ int hist[512];
  __shared__ unsigned long long cand[CAP];
  __shared__ int sel[NK];
  __shared__ int s_cnt, s_B1, s_filled;
  __shared__ unsigned char s_flag[1024];
  // t2-role LDS
  __shared__ unsigned s_max[NM];
  __shared__ float4 s_t[NM];
  __shared__ float s_ta[NM];
  // shared reduce scratch
  __shared__ float swave[16];

  int bx = blockIdx.x;
  int tid = threadIdx.x;

  if (bx < POS_BLOCKS) {
    // ========== pos role: single-compute register-cached IoUs, exact top-50, bag loss ======
    int bm = bx;
    int b = bm >> 5;
    float4 t = tgt[bm];
    float ta = (t.z - t.x) * (t.w - t.y);

    if (tid < 512) hist[tid] = 0;
    if (tid == 0) s_cnt = 0;
    __syncthreads();

    // ONE IoU computation per anchor, cached in registers (static indexing only).
    float riou[32];
#pragma unroll
    for (int k = 0; k < 32; ++k) {
      float4 p = anc[tid + k * 1024];
      float hx = 0.5f * p.z, hy = 0.5f * p.w;
      float x0 = p.x - hx, y0 = p.y - hy, x1 = p.x + hx, y1 = p.y + hy;
      float ba = (x1 - x0) * (y1 - y0);
      float v = iou_corner(t.x, t.y, t.z, t.w, ta, x0, y0, x1, y1, ba);
      riou[k] = v;
      if (v > 0.f) atomicAdd(&hist[(int)(__float_as_uint(v) >> 21)], 1);
    }
    __syncthreads();

    if (tid == 0) {
      int cum = 0, b1 = 0;
      for (int bin = 511; bin >= 0; --bin) {
        cum += hist[bin];
        if (cum >= NK) { b1 = bin; break; }
      }
      s_B1 = b1;
      s_filled = cum;
    }
    __syncthreads();
    int B1 = s_B1;
    bool zero_path = (s_filled < NK);

    // Collect candidates from registers: key = (valbits<<32) | ~idx.
#pragma unroll
    for (int k = 0; k < 32; ++k) {
      float v = riou[k];
      if (v > 0.f) {
        unsigned vb = __float_as_uint(v);
        if ((int)(vb >> 21) >= B1) {
          int slot = atomicAdd(&s_cnt, 1);
          if (slot < CAP)
            cand[slot] = ((unsigned long long)vb << 32) | (unsigned)(~(tid + k * 1024));
        }
      }
    }
    __syncthreads();
    int n = min(s_cnt, CAP);

    // Rank pass (keys unique): rank<NK -> selected.
    for (int c = tid; c < n; c += 1024) {
      unsigned long long key = cand[c];
      int rank = 0;
      for (int j = 0; j < n; ++j) rank += (cand[j] > key);
      if (rank < NK) sel[rank] = (int)(~(unsigned)(key & 0xFFFFFFFFull));
    }
    __syncthreads();

    // Degenerate fill (cold): smallest-index zero-IoU anchors; unrolled, s_filled-guarded.
    if (zero_path) {
      if (tid == 0) s_filled = n;
      __syncthreads();
#pragma unroll
      for (int k = 0; k < 32; ++k) {
        if (s_filled < NK) {      // uniform: s_filled only changes before a barrier
          s_flag[tid] = (riou[k] == 0.f);
          __syncthreads();
          if (tid == 0) {
            int base = k * 1024;
            for (int i = 0; i < 1024 && s_filled < NK; ++i)
              if (s_flag[i]) sel[s_filled++] = base + i;
          }
          __syncthreads();
        }
      }
    }

    // Bag loss on wave 0 (lanes 0..49 active).
    if (tid < 64) {
      int lane = tid;
      float lg = 0.f, wr = 0.f;
      if (lane < NK) {
        int a = sel[lane];
        int lb = labels[bm];
        float4 p = anc[a];
        float4 l = br[(size_t)b * NA + a];
        float logit = cls[((size_t)b * NA + a) * NC + lb];
        float mc = 1.f / (1.f + __expf(-logit));
        float gx = ((t.x + t.z) * 0.5f - p.x) / (VAR0 * p.z);
        float gy = ((t.y + t.w) * 0.5f - p.y) / (VAR0 * p.w);
        float gw = __logf((t.z - t.x) / p.z) / VAR1;
        float gh = __logf((t.w - t.y) / p.w) / VAR1;
        float v0 = gx - l.x, v1 = gy - l.y, v2 = gw - l.z, v3 = gh - l.w;
        float rl = 0.f;
        {
          float av;
          av = fabsf(v0); rl += (av < SL1B) ? (0.5f / SL1B) * v0 * v0 : (av - 0.5f * SL1B);
          av = fabsf(v1); rl += (av < SL1B) ? (0.5f / SL1B) * v1 * v1 : (av - 0.5f * SL1B);
          av = fabsf(v2); rl += (av < SL1B) ? (0.5f / SL1B) * v2 * v2 : (av - 0.5f * SL1B);
          av = fabsf(v3); rl += (av < SL1B) ? (0.5f / SL1B) * v3 * v3 : (av - 0.5f * SL1B);
        }
        rl *= SL1W;
        lg = mc * __expf(-rl);
        wr = 1.f / fmaxf(1.f - lg, FEPS);
      }
      float swl = wr * lg, swr = wr;
      for (int off = 32; off; off >>= 1) { swl += __shfl_down(swl, off); swr += __shfl_down(swr, off); }
      if (lane == 0) {
        float bag = swl / swr;
        posp[bm] = -fmaxf(logf(fmaxf(bag, 1e-38f)), -100.f);   // non-atomic partial
      }
    }

  } else if (bx < POS_BLOCKS + T2_BLOCKS) {
    // ========== t2 role: decode per (b,a); per-(b,m) partial max; pairmask ==========
    int t2i = bx - POS_BLOCKS;
    int b = t2i >> 5;
    int chunk = t2i & 31;
    if (tid < NM) {
      float4 t = tgt[b * NM + tid];
      s_t[tid] = t;
      s_ta[tid] = (t.z - t.x) * (t.w - t.y);
      s_max[tid] = 0u;
    }
    __syncthreads();

    int a = chunk * 1024 + tid;
    float4 p = anc[a];
    float4 l = br[(size_t)b * NA + a];
    float cx = p.x + l.x * VAR0 * p.z;
    float cy = p.y + l.y * VAR0 * p.w;
    float w = p.z * __expf(l.z * VAR1);
    float h = p.w * __expf(l.w * VAR1);
    float dx0 = cx - 0.5f * w, dy0 = cy - 0.5f * h;
    float dx1 = cx + 0.5f * w, dy1 = cy + 0.5f * h;
    float da = (dx1 - dx0) * (dy1 - dy0);

    unsigned mymask = 0u;
#pragma unroll
    for (int mm = 0; mm < NM; ++mm) {
      int m = (tid + mm) & (NM - 1);           // stagger over LDS bins
      float4 t = s_t[m];
      float iou = iou_corner(t.x, t.y, t.z, t.w, s_ta[m], dx0, dy0, dx1, dy1, da);
      if (iou > T1f) mymask |= 1u << m;
      atomicMax(&s_max[m], __float_as_uint(iou));  // iou>=0: uint order == float order
    }
    pairmask[(size_t)b * NA + a] = mymask;
    __syncthreads();
    if (tid < NM)
      partmax[((size_t)b * NM + tid) * TB + chunk] = s_max[tid];   // non-atomic

  } else {
    // ========== f0 role: baseline focal sum (bp=0), coalesced ==========
    int fb = bx - POS_BLOCKS - T2_BLOCKS;
    constexpr int NTOT4 = NB * NA * NC / 4;      // 5,242,880 float4s
    const float4* cls4 = (const float4*)cls;
    int stride = F0BLKS * 1024;
    float accum = 0.f;
    for (int i = fb * 1024 + tid; i < NTOT4; i += stride) {
      float4 v = cls4[i];
      float s0 = 1.f / (1.f + __expf(-v.x));
      float s1 = 1.f / (1.f + __expf(-v.y));
      float s2 = 1.f / (1.f + __expf(-v.z));
      float s3 = 1.f / (1.f + __expf(-v.w));
      accum += focal_term(s0, 0.f) + focal_term(s1, 0.f) +
               focal_term(s2, 0.f) + focal_term(s3, 0.f);
    }
    for (int off = 32; off; off >>= 1) accum += __shfl_down(accum, off);
    if ((tid & 63) == 0) swave[tid >> 6] = accum;
    __syncthreads();
    if (tid == 0) {
      float s = 0.f;
#pragma unroll
      for (int i = 0; i < 16; ++i) s += swave[i];
      f0part[fb] = s;                              // non-atomic partial
    }
  }
}

// ---- K2: sparse correction where bp > 0 (atomic-free partials) ----
__global__ void __launch_bounds__(256) corr_kernel(const float4* __restrict__ br,
                                                   const float* __restrict__ cls,
                                                   const float4* __restrict__ anc,
                                                   const float4* __restrict__ tgt,
                                                   const int* __restrict__ labels,
                                                   const unsigned* __restrict__ partmax,
                                                   const unsigned* __restrict__ pairmask,
                                                   float* __restrict__ corrp) {
  __shared__ float4 s_t[NM];
  __shared__ float s_ta[NM], s_inv[NM];
  __shared__ unsigned s_cmask[NC];
  __shared__ unsigned s_maxm[NM];
  __shared__ unsigned s_slotmask[NM];
  __shared__ int s_slotclass[NM];
  __shared__ int s_nslots;
  int b = blockIdx.y;
  int tid = threadIdx.x;
  if (tid < NC) s_cmask[tid] = 0u;
  if (tid < NM) s_maxm[tid] = 0u;
  if (tid == 0) s_nslots = 0;
  __syncthreads();
  if (tid < NM) {
    float4 t = tgt[b * NM + tid];
    s_t[tid] = t;
    s_ta[tid] = (t.z - t.x) * (t.w - t.y);
    atomicOr(&s_cmask[labels[b * NM + tid]], 1u << tid);
  }
  {
    int m = tid >> 3, j = tid & 7;
    const unsigned* pm = &partmax[((size_t)b * NM + m) * TB];
    unsigned mx = 0u;
    for (int k = j; k < TB; k += 8) mx = max(mx, pm[k]);
    atomicMax(&s_maxm[m], mx);
  }
  __syncthreads();
  if (tid < NM) {
    float mxf = __uint_as_float(s_maxm[tid]);
    s_inv[tid] = 1.0f / (fmaxf(mxf, T1f) - T1f);   // T1+1e-12 rounds to 0.5f in fp32
  }
  __syncthreads();
  if (tid < NC && s_cmask[tid] != 0u) {
    int slot = atomicAdd(&s_nslots, 1);
    s_slotmask[slot] = s_cmask[tid];
    s_slotclass[slot] = tid;
  }
  __syncthreads();
  int nslots = s_nslots;

  int a = blockIdx.x * 256 + tid;
  unsigned mk32 = pairmask[(size_t)b * NA + a];
  float accum = 0.f;
  if (mk32) {
    float4 p = anc[a];
    float4 l = br[(size_t)b * NA + a];
    float cx = p.x + l.x * VAR0 * p.z;
    float cy = p.y + l.y * VAR0 * p.w;
    float w = p.z * __expf(l.z * VAR1);
    float h = p.w * __expf(l.w * VAR1);
    float dx0 = cx - 0.5f * w, dy0 = cy - 0.5f * h;
    float dx1 = cx + 0.5f * w, dy1 = cy + 0.5f * h;
    float da = (dx1 - dx0) * (dy1 - dy0);
    for (int j = 0; j < nslots; ++j) {
      unsigned sm = mk32 & s_slotmask[j];
      if (!sm) continue;
      float bp = 0.f;
      while (sm) {
        int m = __ffs(sm) - 1;
        sm &= sm - 1;
        float4 t = s_t[m];
        float iou = iou_corner(t.x, t.y, t.z, t.w, s_ta[m], dx0, dy0, dx1, dy1, da);
        float o = (iou - T1f) * s_inv[m];
        bp = fmaxf(bp, fminf(fmaxf(o, 0.f), 1.f));
      }
      if (bp > 0.f) {
        float logit = cls[((size_t)b * NA + a) * NC + s_slotclass[j]];
        float s = 1.f / (1.f + __expf(-logit));
        accum += focal_term(s, bp) - focal_term(s, 0.f);
      }
    }
  }
  for (int off = 32; off; off >>= 1) accum += __shfl_down(accum, off);
  __shared__ float swv[4];
  if ((tid & 63) == 0) swv[tid >> 6] = accum;
  __syncthreads();
  if (tid == 0)
    corrp[(size_t)b * CORRB + blockIdx.x] = swv[0] + swv[1] + swv[2] + swv[3];  // non-atomic
}

// ---- K3: finalize — sum all partials in double ----
__global__ void __launch_bounds__(256) fin_kernel(const float* __restrict__ posp,
                                                  const float* __restrict__ f0part,
                                                  const float* __restrict__ corrp,
                                                  float* __restrict__ out) {
  int tid = threadIdx.x;
  double sp = 0.0, sn = 0.0;
  for (int i = tid; i < POS_BLOCKS; i += 256) sp += (double)posp[i];
  for (int i = tid; i < F0BLKS; i += 256) sn += (double)f0part[i];
  for (int i = tid; i < NB * CORRB; i += 256) sn += (double)corrp[i];
  for (int off = 32; off; off >>= 1) { sp += __shfl_down(sp, off); sn += __shfl_down(sn, off); }
  __shared__ double swp[4], swn[4];
  if ((tid & 63) == 0) { swp[tid >> 6] = sp; swn[tid >> 6] = sn; }
  __syncthreads();
  if (tid == 0) {
    double pos = swp[0] + swp[1] + swp[2] + swp[3];
    double neg = swn[0] + swn[1] + swn[2] + swn[3];
    out[0] = (float)(pos / 256.0 * 0.5);
    out[1] = (float)(neg / 12800.0 * 0.5);
  }
}

extern "C" void kernel_launch(void* const* d_in, const int* in_sizes, int n_in,
                              void* d_out, int out_size, void* d_ws, size_t ws_size,
                              hipStream_t stream) {
  const float4* br  = (const float4*)d_in[0];
  const float*  cls = (const float*)d_in[1];
  const float4* anc = (const float4*)d_in[2];
  const float4* tgt = (const float4*)d_in[3];
  const int*    lab = (const int*)d_in[4];
  float* out = (float*)d_out;
  // workspace layout — every slot written on every call (no init needed):
  float*    posp     = (float*)d_ws;                          // 256 f32
  float*    f0part   = (float*)((char*)d_ws + 4096);          // 512 f32
  float*    corrp    = (float*)((char*)d_ws + 8192);          // 1024 f32
  unsigned* partmax  = (unsigned*)((char*)d_ws + 16384);      // NB*NM*TB u32 = 32 KB
  unsigned* pairmask = (unsigned*)((char*)d_ws + 65536);      // NB*NA u32 = 1 MB

  mega_kernel<<<dim3(POS_BLOCKS + T2_BLOCKS + F0BLKS), 1024, 0, stream>>>(
      br, cls, anc, tgt, lab, partmax, pairmask, posp, f0part);
  corr_kernel<<<dim3(CORRB, NB), 256, 0, stream>>>(br, cls, anc, tgt, lab, partmax, pairmask, corrp);
  fin_kernel<<<1, 256, 0, stream>>>(posp, f0part, corrp, out);
}

// Round 9
// 58.567 us; speedup vs baseline: 1.0654x; 1.0654x over previous
//
#include <hip/hip_runtime.h>

#define NB 8
#define NA 32768
#define NC 80
#define NM 32
#define NK 50
#define CAP 4096
#define TB 32                 // t2 chunks per image (1024 anchors each)
#define NBLK 512              // mega grid: 256 pos + 256 t2; all do f0 slices
#define CORRB (NA / 256)      // 128 corr blocks per image
constexpr float VAR0 = 0.1f, VAR1 = 0.2f;
constexpr float T1f  = 0.5f;
constexpr float SL1B = 0.11f;
constexpr float SL1W = 0.75f;
constexpr float FEPS = 1e-12f;

__device__ __forceinline__ float iou_corner(float tx0, float ty0, float tx1, float ty1, float ta,
                                            float bx0, float by0, float bx1, float by1, float ba) {
  float lx = fmaxf(tx0, bx0), ly = fmaxf(ty0, by0);
  float rx = fminf(tx1, bx1), ry = fminf(ty1, by1);
  float wx = fmaxf(rx - lx, 0.f), wy = fmaxf(ry - ly, 0.f);
  float inter = wx * wy;
  return inter / (ta + ba - inter);
}

// __noinline__ so pos-role's multi-pass recomputations are bit-identical.
__device__ __noinline__ float anchor_iou(float4 p, float tx0, float ty0, float tx1, float ty1, float ta) {
  float hx = 0.5f * p.z, hy = 0.5f * p.w;
  float x0 = p.x - hx, y0 = p.y - hy, x1 = p.x + hx, y1 = p.y + hy;
  float ba = (x1 - x0) * (y1 - y0);
  return iou_corner(tx0, ty0, tx1, ty1, ta, x0, y0, x1, y1, ba);
}

__device__ __forceinline__ float focal_term(float s, float bp) {
  float pr = s * (1.f - bp);
  float om = fmaxf(1.f - pr, 1e-38f);
  return pr * pr * fminf(-__logf(om), 100.f);
}

__device__ __forceinline__ float focal4(float4 v) {
  float s0 = 1.f / (1.f + __expf(-v.x));
  float s1 = 1.f / (1.f + __expf(-v.y));
  float s2 = 1.f / (1.f + __expf(-v.z));
  float s3 = 1.f / (1.f + __expf(-v.w));
  return focal_term(s0, 0.f) + focal_term(s1, 0.f) + focal_term(s2, 0.f) + focal_term(s3, 0.f);
}

// ---- K1: every block streams an f0 slice first (t=0 machine-wide), then its role ----
__global__ void __launch_bounds__(1024, 8) mega_kernel(const float4* __restrict__ br,
                                                       const float* __restrict__ cls,
                                                       const float4* __restrict__ anc,
                                                       const float4* __restrict__ tgt,
                                                       const int* __restrict__ labels,
                                                       unsigned* __restrict__ partmax,
                                                       unsigned* __restrict__ pairmask,
                                                       float* __restrict__ posp,
                                                       float* __restrict__ f0part) {
  // pos-role LDS (largest role dominates; ~37 KB total)
  __shared__ int hist[512];
  __shared__ unsigned long long cand[CAP];
  __shared__ int sel[NK];
  __shared__ int s_cnt, s_B1, s_filled;
  __shared__ unsigned char s_flag[1024];
  // t2-role LDS
  __shared__ unsigned s_max[NM];
  __shared__ float4 s_t[NM];
  __shared__ float s_ta[NM];
  // reduce scratch
  __shared__ float swave[16];

  int bx = blockIdx.x;
  int tid = threadIdx.x;

  // ================= phase A (all blocks): f0 slice, two 5-deep load batches ============
  {
    const float4* cls4 = (const float4*)cls;
    constexpr int STRIDE = NBLK * 1024;           // 524288; NTOT4/STRIDE == 10 exactly
    int base = bx * 1024 + tid;
    float4 v0 = cls4[base + 0 * STRIDE];
    float4 v1 = cls4[base + 1 * STRIDE];
    float4 v2 = cls4[base + 2 * STRIDE];
    float4 v3 = cls4[base + 3 * STRIDE];
    float4 v4 = cls4[base + 4 * STRIDE];
    float accum = focal4(v0) + focal4(v1) + focal4(v2) + focal4(v3) + focal4(v4);
    float4 w0 = cls4[base + 5 * STRIDE];
    float4 w1 = cls4[base + 6 * STRIDE];
    float4 w2 = cls4[base + 7 * STRIDE];
    float4 w3 = cls4[base + 8 * STRIDE];
    float4 w4 = cls4[base + 9 * STRIDE];
    accum += focal4(w0) + focal4(w1) + focal4(w2) + focal4(w3) + focal4(w4);
    for (int off = 32; off; off >>= 1) accum += __shfl_down(accum, off);
    if ((tid & 63) == 0) swave[tid >> 6] = accum;
    __syncthreads();
    if (tid == 0) {
      float s = 0.f;
#pragma unroll
      for (int i = 0; i < 16; ++i) s += swave[i];
      f0part[bx] = s;                              // non-atomic partial
    }
    __syncthreads();
  }

  if (bx < NB * NM) {
    // ================= pos role: histogram-select exact top-50 + bag loss =================
    int bm = bx;
    int b = bm >> 5;
    float4 t = tgt[bm];
    float ta = (t.z - t.x) * (t.w - t.y);

    if (tid < 512) hist[tid] = 0;
    if (tid == 0) s_cnt = 0;
    __syncthreads();

    for (int a = tid; a < NA; a += 1024) {
      float iou = anchor_iou(anc[a], t.x, t.y, t.z, t.w, ta);
      if (iou > 0.f) {
        int bin = (int)(__float_as_uint(iou) >> 21);
        atomicAdd(&hist[bin], 1);
      }
    }
    __syncthreads();

    if (tid == 0) {
      int cum = 0, b1 = 0;
      for (int bin = 511; bin >= 0; --bin) {
        cum += hist[bin];
        if (cum >= NK) { b1 = bin; break; }
      }
      s_B1 = b1;
      s_filled = cum;
    }
    __syncthreads();
    int B1 = s_B1;
    bool zero_path = (s_filled < NK);

    for (int a = tid; a < NA; a += 1024) {
      float iou = anchor_iou(anc[a], t.x, t.y, t.z, t.w, ta);
      if (iou > 0.f) {
        unsigned vb = __float_as_uint(iou);
        if ((int)(vb >> 21) >= B1) {
          int slot = atomicAdd(&s_cnt, 1);
          if (slot < CAP)
            cand[slot] = ((unsigned long long)vb << 32) | (unsigned)(~a);
        }
      }
    }
    __syncthreads();
    int n = min(s_cnt, CAP);

    for (int c = tid; c < n; c += 1024) {
      unsigned long long key = cand[c];
      int rank = 0;
      for (int j = 0; j < n; ++j) rank += (cand[j] > key);
      if (rank < NK) sel[rank] = (int)(~(unsigned)(key & 0xFFFFFFFFull));
    }
    __syncthreads();

    if (zero_path) {
      if (tid == 0) s_filled = n;
      __syncthreads();
      for (int base = 0; base < NA; base += 1024) {
        int a = base + tid;
        float iou = anchor_iou(anc[a], t.x, t.y, t.z, t.w, ta);
        s_flag[tid] = (iou == 0.f);
        __syncthreads();
        if (tid == 0) {
          for (int i = 0; i < 1024 && s_filled < NK; ++i)
            if (s_flag[i]) { sel[s_filled++] = base + i; }
        }
        __syncthreads();
        if (s_filled >= NK) break;
      }
    }

    if (tid < 64) {
      int lane = tid;
      float lg = 0.f, wr = 0.f;
      if (lane < NK) {
        int a = sel[lane];
        int lb = labels[bm];
        float4 p = anc[a];
        float4 l = br[(size_t)b * NA + a];
        float logit = cls[((size_t)b * NA + a) * NC + lb];
        float mc = 1.f / (1.f + __expf(-logit));
        float gx = ((t.x + t.z) * 0.5f - p.x) / (VAR0 * p.z);
        float gy = ((t.y + t.w) * 0.5f - p.y) / (VAR0 * p.w);
        float gw = __logf((t.z - t.x) / p.z) / VAR1;
        float gh = __logf((t.w - t.y) / p.w) / VAR1;
        float v0 = gx - l.x, v1 = gy - l.y, v2 = gw - l.z, v3 = gh - l.w;
        float rl = 0.f;
        {
          float av;
          av = fabsf(v0); rl += (av < SL1B) ? (0.5f / SL1B) * v0 * v0 : (av - 0.5f * SL1B);
          av = fabsf(v1); rl += (av < SL1B) ? (0.5f / SL1B) * v1 * v1 : (av - 0.5f * SL1B);
          av = fabsf(v2); rl += (av < SL1B) ? (0.5f / SL1B) * v2 * v2 : (av - 0.5f * SL1B);
          av = fabsf(v3); rl += (av < SL1B) ? (0.5f / SL1B) * v3 * v3 : (av - 0.5f * SL1B);
        }
        rl *= SL1W;
        lg = mc * __expf(-rl);
        wr = 1.f / fmaxf(1.f - lg, FEPS);
      }
      float swl = wr * lg, swr = wr;
      for (int off = 32; off; off >>= 1) { swl += __shfl_down(swl, off); swr += __shfl_down(swr, off); }
      if (lane == 0) {
        float bag = swl / swr;
        posp[bm] = -fmaxf(logf(fmaxf(bag, 1e-38f)), -100.f);   // non-atomic partial
      }
    }

  } else {
    // ================= t2 role: decode per (b,a); per-(b,m) partial max; pairmask ==========
    int t2i = bx - NB * NM;
    int b = t2i >> 5;
    int chunk = t2i & 31;
    if (tid < NM) {
      float4 t = tgt[b * NM + tid];
      s_t[tid] = t;
      s_ta[tid] = (t.z - t.x) * (t.w - t.y);
      s_max[tid] = 0u;
    }
    __syncthreads();

    int a = chunk * 1024 + tid;
    float4 p = anc[a];
    float4 l = br[(size_t)b * NA + a];
    float cx = p.x + l.x * VAR0 * p.z;
    float cy = p.y + l.y * VAR0 * p.w;
    float w = p.z * __expf(l.z * VAR1);
    float h = p.w * __expf(l.w * VAR1);
    float dx0 = cx - 0.5f * w, dy0 = cy - 0.5f * h;
    float dx1 = cx + 0.5f * w, dy1 = cy + 0.5f * h;
    float da = (dx1 - dx0) * (dy1 - dy0);

    unsigned mymask = 0u;
#pragma unroll
    for (int mm = 0; mm < NM; ++mm) {
      int m = (tid + mm) & (NM - 1);           // stagger over LDS bins
      float4 t = s_t[m];
      float iou = iou_corner(t.x, t.y, t.z, t.w, s_ta[m], dx0, dy0, dx1, dy1, da);
      if (iou > T1f) mymask |= 1u << m;
      atomicMax(&s_max[m], __float_as_uint(iou));  // iou>=0: uint order == float order
    }
    pairmask[(size_t)b * NA + a] = mymask;
    __syncthreads();
    if (tid < NM)
      partmax[((size_t)b * NM + tid) * TB + chunk] = s_max[tid];   // non-atomic
  }
}

// ---- K2: sparse correction where bp > 0 (atomic-free partials) ----
__global__ void __launch_bounds__(256) corr_kernel(const float4* __restrict__ br,
                                                   const float* __restrict__ cls,
                                                   const float4* __restrict__ anc,
                                                   const float4* __restrict__ tgt,
                                                   const int* __restrict__ labels,
                                                   const unsigned* __restrict__ partmax,
                                                   const unsigned* __restrict__ pairmask,
                                                   float* __restrict__ corrp) {
  __shared__ float4 s_t[NM];
  __shared__ float s_ta[NM], s_inv[NM];
  __shared__ unsigned s_cmask[NC];
  __shared__ unsigned s_maxm[NM];
  __shared__ unsigned s_slotmask[NM];
  __shared__ int s_slotclass[NM];
  __shared__ int s_nslots;
  int b = blockIdx.y;
  int tid = threadIdx.x;
  if (tid < NC) s_cmask[tid] = 0u;
  if (tid < NM) s_maxm[tid] = 0u;
  if (tid == 0) s_nslots = 0;
  __syncthreads();
  if (tid < NM) {
    float4 t = tgt[b * NM + tid];
    s_t[tid] = t;
    s_ta[tid] = (t.z - t.x) * (t.w - t.y);
    atomicOr(&s_cmask[labels[b * NM + tid]], 1u << tid);
  }
  {
    int m = tid >> 3, j = tid & 7;
    const unsigned* pm = &partmax[((size_t)b * NM + m) * TB];
    unsigned mx = 0u;
    for (int k = j; k < TB; k += 8) mx = max(mx, pm[k]);
    atomicMax(&s_maxm[m], mx);
  }
  __syncthreads();
  if (tid < NM) {
    float mxf = __uint_as_float(s_maxm[tid]);
    s_inv[tid] = 1.0f / (fmaxf(mxf, T1f) - T1f);   // T1+1e-12 rounds to 0.5f in fp32
  }
  __syncthreads();
  if (tid < NC && s_cmask[tid] != 0u) {
    int slot = atomicAdd(&s_nslots, 1);
    s_slotmask[slot] = s_cmask[tid];
    s_slotclass[slot] = tid;
  }
  __syncthreads();
  int nslots = s_nslots;

  int a = blockIdx.x * 256 + tid;
  unsigned mk32 = pairmask[(size_t)b * NA + a];
  float accum = 0.f;
  if (mk32) {
    float4 p = anc[a];
    float4 l = br[(size_t)b * NA + a];
    float cx = p.x + l.x * VAR0 * p.z;
    float cy = p.y + l.y * VAR0 * p.w;
    float w = p.z * __expf(l.z * VAR1);
    float h = p.w * __expf(l.w * VAR1);
    float dx0 = cx - 0.5f * w, dy0 = cy - 0.5f * h;
    float dx1 = cx + 0.5f * w, dy1 = cy + 0.5f * h;
    float da = (dx1 - dx0) * (dy1 - dy0);
    for (int j = 0; j < nslots; ++j) {
      unsigned sm = mk32 & s_slotmask[j];
      if (!sm) continue;
      float bp = 0.f;
      while (sm) {
        int m = __ffs(sm) - 1;
        sm &= sm - 1;
        float4 t = s_t[m];
        float iou = iou_corner(t.x, t.y, t.z, t.w, s_ta[m], dx0, dy0, dx1, dy1, da);
        float o = (iou - T1f) * s_inv[m];
        bp = fmaxf(bp, fminf(fmaxf(o, 0.f), 1.f));
      }
      if (bp > 0.f) {
        float logit = cls[((size_t)b * NA + a) * NC + s_slotclass[j]];
        float s = 1.f / (1.f + __expf(-logit));
        accum += focal_term(s, bp) - focal_term(s, 0.f);
      }
    }
  }
  for (int off = 32; off; off >>= 1) accum += __shfl_down(accum, off);
  __shared__ float swv[4];
  if ((tid & 63) == 0) swv[tid >> 6] = accum;
  __syncthreads();
  if (tid == 0)
    corrp[(size_t)b * CORRB + blockIdx.x] = swv[0] + swv[1] + swv[2] + swv[3];  // non-atomic
}

// ---- K3: finalize — sum all partials in double ----
__global__ void __launch_bounds__(256) fin_kernel(const float* __restrict__ posp,
                                                  const float* __restrict__ f0part,
                                                  const float* __restrict__ corrp,
                                                  float* __restrict__ out) {
  int tid = threadIdx.x;
  double sp = 0.0, sn = 0.0;
  for (int i = tid; i < NB * NM; i += 256) sp += (double)posp[i];
  for (int i = tid; i < NBLK; i += 256) sn += (double)f0part[i];
  for (int i = tid; i < NB * CORRB; i += 256) sn += (double)corrp[i];
  for (int off = 32; off; off >>= 1) { sp += __shfl_down(sp, off); sn += __shfl_down(sn, off); }
  __shared__ double swp[4], swn[4];
  if ((tid & 63) == 0) { swp[tid >> 6] = sp; swn[tid >> 6] = sn; }
  __syncthreads();
  if (tid == 0) {
    double pos = swp[0] + swp[1] + swp[2] + swp[3];
    double neg = swn[0] + swn[1] + swn[2] + swn[3];
    out[0] = (float)(pos / 256.0 * 0.5);
    out[1] = (float)(neg / 12800.0 * 0.5);
  }
}

extern "C" void kernel_launch(void* const* d_in, const int* in_sizes, int n_in,
                              void* d_out, int out_size, void* d_ws, size_t ws_size,
                              hipStream_t stream) {
  const float4* br  = (const float4*)d_in[0];
  const float*  cls = (const float*)d_in[1];
  const float4* anc = (const float4*)d_in[2];
  const float4* tgt = (const float4*)d_in[3];
  const int*    lab = (const int*)d_in[4];
  float* out = (float*)d_out;
  // workspace layout — every slot written on every call (no init needed):
  float*    posp     = (float*)d_ws;                          // 256 f32
  float*    f0part   = (float*)((char*)d_ws + 4096);          // 512 f32
  float*    corrp    = (float*)((char*)d_ws + 8192);          // 1024 f32
  unsigned* partmax  = (unsigned*)((char*)d_ws + 16384);      // NB*NM*TB u32 = 32 KB
  unsigned* pairmask = (unsigned*)((char*)d_ws + 65536);      // NB*NA u32 = 1 MB

  mega_kernel<<<dim3(NBLK), 1024, 0, stream>>>(
      br, cls, anc, tgt, lab, partmax, pairmask, posp, f0part);
  corr_kernel<<<dim3(CORRB, NB), 256, 0, stream>>>(br, cls, anc, tgt, lab, partmax, pairmask, corrp);
  fin_kernel<<<1, 256, 0, stream>>>(posp, f0part, corrp, out);
}